// Round 7
// baseline (587.845 us; speedup 1.0000x reference)
//
#include <hip/hip_runtime.h>
#include <math.h>

#define N_NODES 50000
#define N_EDGES 500000
#define NPB 16      // nodes per conv block (50000 = 16 * 3125)
#define GROUPS 8    // 32-lane groups per 256-thread block

__device__ __forceinline__ float gelu_fast(float x) {
    // gelu tanh-approximation; tanh(z) = 1 - 2/(1+e^{2z}) with fast exp/rcp
    const float k0 = 0.7978845608028654f;
    const float k1 = 0.044715f;
    float z2 = 2.f * k0 * (x + k1 * x * x * x);
    float ez = __expf(z2);
    float th = 1.f - 2.f * __builtin_amdgcn_rcpf(ez + 1.f);
    return 0.5f * x * (1.f + th);
}

__device__ __forceinline__ unsigned short f2bf(float x) {
    unsigned int u = __float_as_uint(x);
    unsigned int r = (u + 0x7FFFu + ((u >> 16) & 1u)) >> 16;  // RNE
    return (unsigned short)r;
}
__device__ __forceinline__ float bf2f(unsigned short b) {
    return __uint_as_float(((unsigned int)b) << 16);
}

// Fire-and-forget native LDS float add (no CAS loop, no return).
__device__ __forceinline__ void lds_add(float* p, float v) {
    unsigned int off = (unsigned int)(size_t)p;
    asm volatile("ds_add_f32 %0, %1" :: "v"(off), "v"(v) : "memory");
}

// K1: per-node lift.
// feat[n*128 + u*4 + {0..3}] = {feat_s[u], feat_v[u][xyz]} ; a*self -> d_out
__global__ void node_pre(const float* __restrict__ node_input,
                         const float* __restrict__ W1_s,
                         const float* __restrict__ W1_v,
                         float* __restrict__ feat,
                         float* __restrict__ out) {
    __shared__ float lWs[32 * 64];
    __shared__ float lWv[32 * 64];
    for (int i = threadIdx.x; i < 2048; i += blockDim.x) {
        lWs[i] = W1_s[i];
        lWv[i] = W1_v[i];
    }
    __syncthreads();
    int n = blockIdx.x * blockDim.x + threadIdx.x;
    if (n >= N_NODES) return;
    const float inv_sqrt_mul = 0.17677669529663687f;  // 1/sqrt(32)
    const float a_mix = 0.9219544457292887f;          // sqrt(0.85)

    float s[32];
#pragma unroll
    for (int u = 0; u < 32; ++u) s[u] = node_input[n * 128 + u];
#pragma unroll 4
    for (int w = 0; w < 64; ++w) {
        float acc = 0.f;
#pragma unroll
        for (int u = 0; u < 32; ++u) acc += s[u] * lWs[u * 64 + w];
        acc *= inv_sqrt_mul;
        if (w < 32) feat[(size_t)n * 128 + w * 4 + 0] = acc;
        else        out[n * 128 + (w - 32)] = a_mix * acc;
    }
#pragma unroll
    for (int k = 0; k < 3; ++k) {
        float vk[32];
#pragma unroll
        for (int u = 0; u < 32; ++u) vk[u] = node_input[n * 128 + 32 + u * 3 + k];
#pragma unroll 4
        for (int w = 0; w < 64; ++w) {
            float acc = 0.f;
#pragma unroll
            for (int u = 0; u < 32; ++u) acc += vk[u] * lWv[u * 64 + w];
            acc *= inv_sqrt_mul;
            if (w < 32) feat[(size_t)n * 128 + w * 4 + 1 + k] = acc;
            else        out[n * 128 + 32 + (w - 32) * 3 + k] = a_mix * acc;
        }
    }
}

// K2a: histogram of edge_dst
__global__ void hist_kernel(const int* __restrict__ edge_dst, int* __restrict__ counts) {
    int e = blockIdx.x * blockDim.x + threadIdx.x;
    if (e < N_EDGES) atomicAdd(&counts[edge_dst[e]], 1);
}

// K2b: exclusive scan of counts -> offsets (N+1) and cursor (N). Single block.
__global__ void scan_kernel(const int* __restrict__ counts,
                            int* __restrict__ offsets,
                            int* __restrict__ cursor) {
    const int T = 1024;
    __shared__ int partial[T];
    int t = threadIdx.x;
    const int chunk = (N_NODES + T - 1) / T;
    int start = t * chunk;
    int end = start + chunk; if (end > N_NODES) end = N_NODES;
    if (start > N_NODES) start = N_NODES;
    int sum = 0;
    for (int i = start; i < end; ++i) sum += counts[i];
    partial[t] = sum;
    __syncthreads();
    for (int off = 1; off < T; off <<= 1) {
        int other = (t >= off) ? partial[t - off] : 0;
        __syncthreads();
        partial[t] += other;
        __syncthreads();
    }
    int run = (t == 0) ? 0 : partial[t - 1];
    for (int i = start; i < end; ++i) {
        offsets[i] = run;
        cursor[i] = run;
        run += counts[i];
    }
    if (t == T - 1) offsets[N_NODES] = run;  // == N_EDGES
}

// K2c: scatter edge data into dst-sorted order.
__global__ void scatter_kernel(const int* __restrict__ edge_src,
                               const int* __restrict__ edge_dst,
                               const float* __restrict__ edge_attr,
                               const float* __restrict__ edge_scalars,
                               int* __restrict__ cursor,
                               float4* __restrict__ sS4,
                               float4* __restrict__ ySorted,
                               int2* __restrict__ srcdst) {
    int e = blockIdx.x * blockDim.x + threadIdx.x;
    if (e >= N_EDGES) return;
    int d = edge_dst[e];
    int pos = atomicAdd(&cursor[d], 1);
    float4 a  = *(const float4*)(edge_attr + (size_t)e * 4);
    float4 s0 = *(const float4*)(edge_scalars + (size_t)e * 8);
    float4 s1 = *(const float4*)(edge_scalars + (size_t)e * 8 + 4);
    ySorted[pos] = a;
    sS4[(size_t)pos * 2 + 0] = s0;
    sS4[(size_t)pos * 2 + 1] = s1;
    srcdst[pos] = make_int2(edge_src[e], d);
}

// K_mlp: one THREAD per sorted edge. Weights read via wave-uniform indices ->
// scalar loads / SGPR operands (no LDS at all). Fast gelu. bf16x4 output.
__global__ void mlp_kernel(const float4* __restrict__ sS4,
                           const float* __restrict__ M0,
                           const float* __restrict__ M1,
                           const float* __restrict__ Wtp0,
                           const float* __restrict__ Wtp1,
                           const float* __restrict__ Wtp2,
                           const float* __restrict__ Wtp3,
                           ushort4* __restrict__ wOut) {
    const int e = blockIdx.x * blockDim.x + threadIdx.x;
    if (e >= N_EDGES) return;

    const float inv_sqrt8  = 0.35355339059327373f;
    const float inv_sqrt32 = 0.17677669529663687f;

    const float4 s0 = sS4[(size_t)e * 2 + 0];
    const float4 s1 = sS4[(size_t)e * 2 + 1];

    // layer 1: t[32] — M0 is [8][32] row-major; indices compile-time => SGPR ops
    float t[32];
#pragma unroll
    for (int u = 0; u < 32; ++u) {
        float acc = s0.x * M0[0 * 32 + u] + s0.y * M0[1 * 32 + u]
                  + s0.z * M0[2 * 32 + u] + s0.w * M0[3 * 32 + u]
                  + s1.x * M0[4 * 32 + u] + s1.y * M0[5 * 32 + u]
                  + s1.z * M0[6 * 32 + u] + s1.w * M0[7 * 32 + u];
        t[u] = gelu_fast(acc * inv_sqrt8);
    }
    // layer 2: h[32] — M1 [32][32]; full unroll (h indices must be static)
    float h[32];
#pragma unroll
    for (int u = 0; u < 32; ++u) {
        float acc = 0.f;
#pragma unroll
        for (int m = 0; m < 32; ++m) acc += t[m] * M1[m * 32 + u];
        h[u] = gelu_fast(acc * inv_sqrt32);
    }
    // layer 3: w0..w3 per u — u runtime (uniform), j unrolled (h[j] static)
    ushort4* wbase = wOut + (size_t)e * 32;
#pragma unroll 1
    for (int u = 0; u < 32; ++u) {
        float ax = 0.f, ay = 0.f, az = 0.f, aw = 0.f;
#pragma unroll
        for (int j = 0; j < 32; ++j) {
            const float hj = h[j];
            ax += hj * Wtp0[j * 32 + u];
            ay += hj * Wtp1[j * 32 + u];
            az += hj * Wtp2[j * 32 + u];
            aw += hj * Wtp3[j * 32 + u];
        }
        ushort4 o;
        o.x = f2bf(ax * inv_sqrt32);
        o.y = f2bf(ay * inv_sqrt32);
        o.z = f2bf(az * inv_sqrt32);
        o.w = f2bf(aw * inv_sqrt32);
        wbase[u] = o;
    }
}

// K_conv: block owns NPB contiguous dst nodes => contiguous edge range.
// Chunked per-group assignment; register run-combining; native ds_add_f32.
__global__ void __launch_bounds__(256)
conv_kernel(const ushort4* __restrict__ wOut,
            const float4* __restrict__ ySorted,
            const int2* __restrict__ srcdst,
            const int* __restrict__ offsets,
            const float* __restrict__ W2_s,
            const float* __restrict__ W2_v,
            const float* __restrict__ feat,
            float* __restrict__ out) {
    __shared__ float sacc[NPB * 256];  // per-node raw accum: [s(64) | v(3*64)]
    for (int i = threadIdx.x; i < NPB * 256; i += blockDim.x) sacc[i] = 0.f;
    __syncthreads();

    const int lane = threadIdx.x & 31;
    const int g = threadIdx.x >> 5;
    const int n0 = blockIdx.x * NPB;
    const int eb = offsets[n0];
    const int ee = offsets[n0 + NPB];
    const float INV3 = 0.5773502691896258f;  // 1/sqrt(3)
    const float4* feat4 = (const float4*)feat;

    const int total = ee - eb;
    const int per = (total + GROUPS - 1) / GROUPS;
    const int es = eb + g * per;
    int et = es + per; if (et > ee) et = ee;

    float r0 = 0.f, r1 = 0.f, r2 = 0.f, r3 = 0.f;
    float r4 = 0.f, r5 = 0.f, r6 = 0.f, r7 = 0.f;
    int cur = -1;

#pragma unroll 2
    for (int e = es; e < et; ++e) {
        const int2 sd = srcdst[e];
        const ushort4 wq = wOut[(size_t)e * 32 + lane];
        const float4 yq = ySorted[e];                  // uniform per group
        const float4 f = feat4[(size_t)sd.x * 32 + lane];

        if (sd.y != cur) {
            if (cur >= 0) {
                float* a = sacc + (cur - n0) * 256;
                lds_add(a + lane, r0);
                lds_add(a + 32 + lane, r1);
                lds_add(a + 64 + lane * 3 + 0, r2);
                lds_add(a + 64 + lane * 3 + 1, r3);
                lds_add(a + 64 + lane * 3 + 2, r4);
                lds_add(a + 160 + lane * 3 + 0, r5);
                lds_add(a + 160 + lane * 3 + 1, r6);
                lds_add(a + 160 + lane * 3 + 2, r7);
            }
            cur = sd.y;
            r0 = r1 = r2 = r3 = r4 = r5 = r6 = r7 = 0.f;
        }

        const float w0 = bf2f(wq.x), w1 = bf2f(wq.y);
        const float w2 = bf2f(wq.z), w3 = bf2f(wq.w);
        const float dvy = f.y * yq.y + f.z * yq.z + f.w * yq.w;
        const float w1es = w1 * f.x;
        const float w2y0 = w2 * yq.x;

        r0 += w0 * f.x * yq.x;
        r1 += w3 * dvy * INV3;
        r2 += w1es * yq.y;
        r3 += w1es * yq.z;
        r4 += w1es * yq.w;
        r5 += w2y0 * f.y;
        r6 += w2y0 * f.z;
        r7 += w2y0 * f.w;
    }
    if (cur >= 0) {
        float* a = sacc + (cur - n0) * 256;
        lds_add(a + lane, r0);
        lds_add(a + 32 + lane, r1);
        lds_add(a + 64 + lane * 3 + 0, r2);
        lds_add(a + 64 + lane * 3 + 1, r3);
        lds_add(a + 64 + lane * 3 + 2, r4);
        lds_add(a + 160 + lane * 3 + 0, r5);
        lds_add(a + 160 + lane * 3 + 1, r6);
        lds_add(a + 160 + lane * 3 + 2, r7);
    }
    asm volatile("s_waitcnt lgkmcnt(0)" ::: "memory");
    __syncthreads();

    // epilogue: per node, conv = (acc*inv_deg) @ W2 / sqrt(64); out += sqrt(MIX)*conv
    const float scale = 0.31622776601683794f * 0.125f * 0.3872983346207417f;
    for (int li = g; li < NPB; li += GROUPS) {
        const float* a = sacc + li * 256;
        float cs = 0.f, cv0 = 0.f, cv1 = 0.f, cv2 = 0.f;
#pragma unroll 8
        for (int j = 0; j < 64; ++j) {
            const float as = a[j];                 // LDS broadcast
            cs += as * __ldg(&W2_s[j * 32 + lane]);
            const float wv = __ldg(&W2_v[j * 32 + lane]);
            cv0 += a[64 + 3 * j + 0] * wv;
            cv1 += a[64 + 3 * j + 1] * wv;
            cv2 += a[64 + 3 * j + 2] * wv;
        }
        float* o = out + (size_t)(n0 + li) * 128;
        o[lane]              += scale * cs;
        o[32 + lane * 3 + 0] += scale * cv0;
        o[32 + lane * 3 + 1] += scale * cv1;
        o[32 + lane * 3 + 2] += scale * cv2;
    }
}

extern "C" void kernel_launch(void* const* d_in, const int* in_sizes, int n_in,
                              void* d_out, int out_size, void* d_ws, size_t ws_size,
                              hipStream_t stream) {
    const float* node_input   = (const float*)d_in[0];
    const float* edge_attr    = (const float*)d_in[1];
    const float* edge_scalars = (const float*)d_in[2];
    const float* W1_s = (const float*)d_in[3];
    const float* W1_v = (const float*)d_in[4];
    const float* M0   = (const float*)d_in[5];
    const float* M1   = (const float*)d_in[6];
    const float* Wtp0 = (const float*)d_in[7];
    const float* Wtp1 = (const float*)d_in[8];
    const float* Wtp2 = (const float*)d_in[9];
    const float* Wtp3 = (const float*)d_in[10];
    const float* W2_s = (const float*)d_in[11];
    const float* W2_v = (const float*)d_in[12];
    const int* edge_src = (const int*)d_in[13];
    const int* edge_dst = (const int*)d_in[14];
    float* out = (float*)d_out;
    float* ws  = (float*)d_ws;

    float*  feat    = ws;                                           // N*128 (25.6 MB)
    float4* sS4     = (float4*)(feat + (size_t)N_NODES * 128);      // E*2 float4 (16 MB)
    float4* ySorted = sS4 + (size_t)N_EDGES * 2;                    // E float4 (8 MB)
    ushort4* wOut   = (ushort4*)(ySorted + N_EDGES);                // E*32 ushort4 (128 MB)
    int2*  srcdst   = (int2*)(wOut + (size_t)N_EDGES * 32);         // E int2 (4 MB)
    int*   counts   = (int*)(srcdst + N_EDGES);                     // N
    int*   offsets  = counts + N_NODES;                             // N+1
    int*   cursor   = offsets + N_NODES + 1;                        // N

    hipMemsetAsync(counts, 0, N_NODES * sizeof(int), stream);

    node_pre<<<(N_NODES + 255) / 256, 256, 0, stream>>>(node_input, W1_s, W1_v,
                                                        feat, out);

    hist_kernel<<<(N_EDGES + 255) / 256, 256, 0, stream>>>(edge_dst, counts);
    scan_kernel<<<1, 1024, 0, stream>>>(counts, offsets, cursor);
    scatter_kernel<<<(N_EDGES + 255) / 256, 256, 0, stream>>>(edge_src, edge_dst,
                                                              edge_attr, edge_scalars,
                                                              cursor, sS4, ySorted, srcdst);

    mlp_kernel<<<(N_EDGES + 255) / 256, 256, 0, stream>>>(sS4, M0, M1,
                                                          Wtp0, Wtp1, Wtp2, Wtp3, wOut);

    conv_kernel<<<N_NODES / NPB, 256, 0, stream>>>(wOut, ySorted, srcdst, offsets,
                                                   W2_s, W2_v, feat, out);
}

// Round 8
// 574.265 us; speedup vs baseline: 1.0236x; 1.0236x over previous
//
#include <hip/hip_runtime.h>
#include <math.h>

#define N_NODES 50000
#define N_EDGES 500000
#define NPB 16      // nodes per conv block (50000 = 16 * 3125)
#define GROUPS 8    // 32-lane groups per 256-thread block

__device__ __forceinline__ float gelu_fast(float x) {
    // gelu tanh-approximation; tanh(z) = 1 - 2/(1+e^{2z}) with fast exp/rcp
    const float k0 = 0.7978845608028654f;
    const float k1 = 0.044715f;
    float z2 = 2.f * k0 * (x + k1 * x * x * x);
    float ez = __expf(z2);
    float th = 1.f - 2.f * __builtin_amdgcn_rcpf(ez + 1.f);
    return 0.5f * x * (1.f + th);
}

__device__ __forceinline__ unsigned short f2bf(float x) {
    unsigned int u = __float_as_uint(x);
    unsigned int r = (u + 0x7FFFu + ((u >> 16) & 1u)) >> 16;  // RNE
    return (unsigned short)r;
}
__device__ __forceinline__ float bf2f(unsigned short b) {
    return __uint_as_float(((unsigned int)b) << 16);
}

// Fire-and-forget native LDS float add (no CAS loop, no return).
__device__ __forceinline__ void lds_add(float* p, float v) {
    unsigned int off = (unsigned int)(size_t)p;
    asm volatile("ds_add_f32 %0, %1" :: "v"(off), "v"(v) : "memory");
}

// K1: per-node lift.
// feat[n*128 + u*4 + {0..3}] = {feat_s[u], feat_v[u][xyz]} ; a*self -> d_out
__global__ void node_pre(const float* __restrict__ node_input,
                         const float* __restrict__ W1_s,
                         const float* __restrict__ W1_v,
                         float* __restrict__ feat,
                         float* __restrict__ out) {
    __shared__ float lWs[32 * 64];
    __shared__ float lWv[32 * 64];
    for (int i = threadIdx.x; i < 2048; i += blockDim.x) {
        lWs[i] = W1_s[i];
        lWv[i] = W1_v[i];
    }
    __syncthreads();
    int n = blockIdx.x * blockDim.x + threadIdx.x;
    if (n >= N_NODES) return;
    const float inv_sqrt_mul = 0.17677669529663687f;  // 1/sqrt(32)
    const float a_mix = 0.9219544457292887f;          // sqrt(0.85)

    float s[32];
#pragma unroll
    for (int u = 0; u < 32; ++u) s[u] = node_input[n * 128 + u];
#pragma unroll 4
    for (int w = 0; w < 64; ++w) {
        float acc = 0.f;
#pragma unroll
        for (int u = 0; u < 32; ++u) acc += s[u] * lWs[u * 64 + w];
        acc *= inv_sqrt_mul;
        if (w < 32) feat[(size_t)n * 128 + w * 4 + 0] = acc;
        else        out[n * 128 + (w - 32)] = a_mix * acc;
    }
#pragma unroll
    for (int k = 0; k < 3; ++k) {
        float vk[32];
#pragma unroll
        for (int u = 0; u < 32; ++u) vk[u] = node_input[n * 128 + 32 + u * 3 + k];
#pragma unroll 4
        for (int w = 0; w < 64; ++w) {
            float acc = 0.f;
#pragma unroll
            for (int u = 0; u < 32; ++u) acc += vk[u] * lWv[u * 64 + w];
            acc *= inv_sqrt_mul;
            if (w < 32) feat[(size_t)n * 128 + w * 4 + 1 + k] = acc;
            else        out[n * 128 + 32 + (w - 32) * 3 + k] = a_mix * acc;
        }
    }
}

// K2a: histogram of edge_dst
__global__ void hist_kernel(const int* __restrict__ edge_dst, int* __restrict__ counts) {
    int e = blockIdx.x * blockDim.x + threadIdx.x;
    if (e < N_EDGES) atomicAdd(&counts[edge_dst[e]], 1);
}

// K2b: exclusive scan of counts -> offsets (N+1) and cursor (N). Single block.
__global__ void scan_kernel(const int* __restrict__ counts,
                            int* __restrict__ offsets,
                            int* __restrict__ cursor) {
    const int T = 1024;
    __shared__ int partial[T];
    int t = threadIdx.x;
    const int chunk = (N_NODES + T - 1) / T;
    int start = t * chunk;
    int end = start + chunk; if (end > N_NODES) end = N_NODES;
    if (start > N_NODES) start = N_NODES;
    int sum = 0;
    for (int i = start; i < end; ++i) sum += counts[i];
    partial[t] = sum;
    __syncthreads();
    for (int off = 1; off < T; off <<= 1) {
        int other = (t >= off) ? partial[t - off] : 0;
        __syncthreads();
        partial[t] += other;
        __syncthreads();
    }
    int run = (t == 0) ? 0 : partial[t - 1];
    for (int i = start; i < end; ++i) {
        offsets[i] = run;
        cursor[i] = run;
        run += counts[i];
    }
    if (t == T - 1) offsets[N_NODES] = run;  // == N_EDGES
}

// K2c: scatter per-edge metadata into dst-sorted order.
// sde[pos] = (src, dst, origEdge, 0); ySorted[pos] = edge_attr[e].
// (edge_scalars are NOT scattered anymore — mlp runs in input order.)
__global__ void scatter_kernel(const int* __restrict__ edge_src,
                               const int* __restrict__ edge_dst,
                               const float* __restrict__ edge_attr,
                               int* __restrict__ cursor,
                               float4* __restrict__ ySorted,
                               int4* __restrict__ sde) {
    int e = blockIdx.x * blockDim.x + threadIdx.x;
    if (e >= N_EDGES) return;
    int d = edge_dst[e];
    int pos = atomicAdd(&cursor[d], 1);
    ySorted[pos] = *(const float4*)(edge_attr + (size_t)e * 4);
    sde[pos] = make_int4(edge_src[e], d, e, 0);
}

// K_mlp: one THREAD per INPUT-ORDER edge (pure map; no sorted data needed).
// Weights via wave-uniform indices -> SGPR operands. Output staged through a
// padded LDS tile so global stores are full 128B lines (layout stays [e][u]).
__global__ void mlp_kernel(const float* __restrict__ edge_scalars,
                           const float* __restrict__ M0,
                           const float* __restrict__ M1,
                           const float* __restrict__ Wtp0,
                           const float* __restrict__ Wtp1,
                           const float* __restrict__ Wtp2,
                           const float* __restrict__ Wtp3,
                           ushort4* __restrict__ wOut) {
    __shared__ ushort4 stage[256][17];  // 17: pad to break bank alignment

    const int e0 = blockIdx.x * 256;
    int e = e0 + threadIdx.x;
    int ec = e < N_EDGES ? e : N_EDGES - 1;  // clamp; OOB threads still sync

    const float inv_sqrt8  = 0.35355339059327373f;
    const float inv_sqrt32 = 0.17677669529663687f;

    const float4 s0 = *(const float4*)(edge_scalars + (size_t)ec * 8);
    const float4 s1 = *(const float4*)(edge_scalars + (size_t)ec * 8 + 4);

    // layer 1: t[32]
    float t[32];
#pragma unroll
    for (int u = 0; u < 32; ++u) {
        float acc = s0.x * M0[0 * 32 + u] + s0.y * M0[1 * 32 + u]
                  + s0.z * M0[2 * 32 + u] + s0.w * M0[3 * 32 + u]
                  + s1.x * M0[4 * 32 + u] + s1.y * M0[5 * 32 + u]
                  + s1.z * M0[6 * 32 + u] + s1.w * M0[7 * 32 + u];
        t[u] = gelu_fast(acc * inv_sqrt8);
    }
    // layer 2: h[32]
    float h[32];
#pragma unroll
    for (int u = 0; u < 32; ++u) {
        float acc = 0.f;
#pragma unroll
        for (int m = 0; m < 32; ++m) acc += t[m] * M1[m * 32 + u];
        h[u] = gelu_fast(acc * inv_sqrt32);
    }
    // layer 3 in two halves of 16 u's; stage in LDS; coalesced copy-out.
#pragma unroll 1
    for (int half = 0; half < 2; ++half) {
#pragma unroll 1
        for (int u1 = 0; u1 < 16; ++u1) {
            const int u = half * 16 + u1;
            float ax = 0.f, ay = 0.f, az = 0.f, aw = 0.f;
#pragma unroll
            for (int j = 0; j < 32; ++j) {
                const float hj = h[j];
                ax += hj * Wtp0[j * 32 + u];
                ay += hj * Wtp1[j * 32 + u];
                az += hj * Wtp2[j * 32 + u];
                aw += hj * Wtp3[j * 32 + u];
            }
            ushort4 o;
            o.x = f2bf(ax * inv_sqrt32);
            o.y = f2bf(ay * inv_sqrt32);
            o.z = f2bf(az * inv_sqrt32);
            o.w = f2bf(aw * inv_sqrt32);
            stage[threadIdx.x][u1] = o;
        }
        __syncthreads();
        // copy-out: 256 edges * 16 ushort4; consecutive 16 lanes write one
        // contiguous 128B chunk => full-line stores, no amplification.
#pragma unroll
        for (int p = 0; p < 16; ++p) {
            const int k = p * 256 + threadIdx.x;
            const int el = k >> 4;
            const int u1 = k & 15;
            const int ge = e0 + el;
            if (ge < N_EDGES)
                wOut[(size_t)ge * 32 + half * 16 + u1] = stage[el][u1];
        }
        __syncthreads();
    }
}

// K_conv: block owns NPB contiguous dst nodes => contiguous edge range.
// Chunked per-group assignment; register run-combining; native ds_add_f32.
// Reads wOut via the orig-edge index (256B-aligned contiguous region).
__global__ void __launch_bounds__(256)
conv_kernel(const ushort4* __restrict__ wOut,
            const float4* __restrict__ ySorted,
            const int4* __restrict__ sde,
            const int* __restrict__ offsets,
            const float* __restrict__ W2_s,
            const float* __restrict__ W2_v,
            const float* __restrict__ feat,
            float* __restrict__ out) {
    __shared__ float sacc[NPB * 256];  // per-node raw accum: [s(64) | v(3*64)]
    for (int i = threadIdx.x; i < NPB * 256; i += blockDim.x) sacc[i] = 0.f;
    __syncthreads();

    const int lane = threadIdx.x & 31;
    const int g = threadIdx.x >> 5;
    const int n0 = blockIdx.x * NPB;
    const int eb = offsets[n0];
    const int ee = offsets[n0 + NPB];
    const float INV3 = 0.5773502691896258f;  // 1/sqrt(3)
    const float4* feat4 = (const float4*)feat;

    const int total = ee - eb;
    const int per = (total + GROUPS - 1) / GROUPS;
    const int es = eb + g * per;
    int et = es + per; if (et > ee) et = ee;

    float r0 = 0.f, r1 = 0.f, r2 = 0.f, r3 = 0.f;
    float r4 = 0.f, r5 = 0.f, r6 = 0.f, r7 = 0.f;
    int cur = -1;

#pragma unroll 2
    for (int e = es; e < et; ++e) {
        const int4 sd = sde[e];
        const ushort4 wq = wOut[(size_t)sd.z * 32 + lane];
        const float4 yq = ySorted[e];                  // uniform per group
        const float4 f = feat4[(size_t)sd.x * 32 + lane];

        if (sd.y != cur) {
            if (cur >= 0) {
                float* a = sacc + (cur - n0) * 256;
                lds_add(a + lane, r0);
                lds_add(a + 32 + lane, r1);
                lds_add(a + 64 + lane * 3 + 0, r2);
                lds_add(a + 64 + lane * 3 + 1, r3);
                lds_add(a + 64 + lane * 3 + 2, r4);
                lds_add(a + 160 + lane * 3 + 0, r5);
                lds_add(a + 160 + lane * 3 + 1, r6);
                lds_add(a + 160 + lane * 3 + 2, r7);
            }
            cur = sd.y;
            r0 = r1 = r2 = r3 = r4 = r5 = r6 = r7 = 0.f;
        }

        const float w0 = bf2f(wq.x), w1 = bf2f(wq.y);
        const float w2 = bf2f(wq.z), w3 = bf2f(wq.w);
        const float dvy = f.y * yq.y + f.z * yq.z + f.w * yq.w;
        const float w1es = w1 * f.x;
        const float w2y0 = w2 * yq.x;

        r0 += w0 * f.x * yq.x;
        r1 += w3 * dvy * INV3;
        r2 += w1es * yq.y;
        r3 += w1es * yq.z;
        r4 += w1es * yq.w;
        r5 += w2y0 * f.y;
        r6 += w2y0 * f.z;
        r7 += w2y0 * f.w;
    }
    if (cur >= 0) {
        float* a = sacc + (cur - n0) * 256;
        lds_add(a + lane, r0);
        lds_add(a + 32 + lane, r1);
        lds_add(a + 64 + lane * 3 + 0, r2);
        lds_add(a + 64 + lane * 3 + 1, r3);
        lds_add(a + 64 + lane * 3 + 2, r4);
        lds_add(a + 160 + lane * 3 + 0, r5);
        lds_add(a + 160 + lane * 3 + 1, r6);
        lds_add(a + 160 + lane * 3 + 2, r7);
    }
    asm volatile("s_waitcnt lgkmcnt(0)" ::: "memory");
    __syncthreads();

    // epilogue: per node, conv = (acc*inv_deg) @ W2 / sqrt(64); out += sqrt(MIX)*conv
    const float scale = 0.31622776601683794f * 0.125f * 0.3872983346207417f;
    for (int li = g; li < NPB; li += GROUPS) {
        const float* a = sacc + li * 256;
        float cs = 0.f, cv0 = 0.f, cv1 = 0.f, cv2 = 0.f;
#pragma unroll 8
        for (int j = 0; j < 64; ++j) {
            const float as = a[j];                 // LDS broadcast
            cs += as * __ldg(&W2_s[j * 32 + lane]);
            const float wv = __ldg(&W2_v[j * 32 + lane]);
            cv0 += a[64 + 3 * j + 0] * wv;
            cv1 += a[64 + 3 * j + 1] * wv;
            cv2 += a[64 + 3 * j + 2] * wv;
        }
        float* o = out + (size_t)(n0 + li) * 128;
        o[lane]              += scale * cs;
        o[32 + lane * 3 + 0] += scale * cv0;
        o[32 + lane * 3 + 1] += scale * cv1;
        o[32 + lane * 3 + 2] += scale * cv2;
    }
}

extern "C" void kernel_launch(void* const* d_in, const int* in_sizes, int n_in,
                              void* d_out, int out_size, void* d_ws, size_t ws_size,
                              hipStream_t stream) {
    const float* node_input   = (const float*)d_in[0];
    const float* edge_attr    = (const float*)d_in[1];
    const float* edge_scalars = (const float*)d_in[2];
    const float* W1_s = (const float*)d_in[3];
    const float* W1_v = (const float*)d_in[4];
    const float* M0   = (const float*)d_in[5];
    const float* M1   = (const float*)d_in[6];
    const float* Wtp0 = (const float*)d_in[7];
    const float* Wtp1 = (const float*)d_in[8];
    const float* Wtp2 = (const float*)d_in[9];
    const float* Wtp3 = (const float*)d_in[10];
    const float* W2_s = (const float*)d_in[11];
    const float* W2_v = (const float*)d_in[12];
    const int* edge_src = (const int*)d_in[13];
    const int* edge_dst = (const int*)d_in[14];
    float* out = (float*)d_out;
    float* ws  = (float*)d_ws;

    float*  feat    = ws;                                           // N*128 (25.6 MB)
    float4* ySorted = (float4*)(feat + (size_t)N_NODES * 128);      // E float4 (8 MB)
    ushort4* wOut   = (ushort4*)(ySorted + N_EDGES);                // E*32 ushort4 (128 MB)
    int4*  sde      = (int4*)(wOut + (size_t)N_EDGES * 32);         // E int4 (8 MB)
    int*   counts   = (int*)(sde + N_EDGES);                        // N
    int*   offsets  = counts + N_NODES;                             // N+1
    int*   cursor   = offsets + N_NODES + 1;                        // N
    // total ~170 MB

    hipMemsetAsync(counts, 0, N_NODES * sizeof(int), stream);

    node_pre<<<(N_NODES + 255) / 256, 256, 0, stream>>>(node_input, W1_s, W1_v,
                                                        feat, out);

    hist_kernel<<<(N_EDGES + 255) / 256, 256, 0, stream>>>(edge_dst, counts);
    scan_kernel<<<1, 1024, 0, stream>>>(counts, offsets, cursor);
    scatter_kernel<<<(N_EDGES + 255) / 256, 256, 0, stream>>>(edge_src, edge_dst,
                                                              edge_attr,
                                                              cursor, ySorted, sde);

    mlp_kernel<<<(N_EDGES + 255) / 256, 256, 0, stream>>>(edge_scalars, M0, M1,
                                                          Wtp0, Wtp1, Wtp2, Wtp3, wOut);

    conv_kernel<<<N_NODES / NPB, 256, 0, stream>>>(wOut, ySorted, sde, offsets,
                                                   W2_s, W2_v, feat, out);
}